// Round 4
// baseline (160.195 us; speedup 1.0000x reference)
//
#include <hip/hip_runtime.h>

#define NNODE 2048
#define DD    512
#define HHID  256
#define LLAT  16
#define H2    32   // 2L

typedef __attribute__((ext_vector_type(8))) short  short8;
typedef __attribute__((ext_vector_type(4))) float  f32x4;

__device__ __forceinline__ unsigned short f2bf(float x) {
    unsigned int u = __float_as_uint(x);
    unsigned int r = (u + 0x7fffu + ((u >> 16) & 1u)) >> 16;  // RNE
    return (unsigned short)r;
}
__device__ __forceinline__ float bf2f(unsigned short u) {
    return __uint_as_float(((unsigned int)u) << 16);
}

// ---------------- T0: convert A, X, W1 to bf16 (grid-stride over float4) ---------
__global__ __launch_bounds__(256) void t0_cvt(const float* __restrict__ A,
                                              const float* __restrict__ X,
                                              const float* __restrict__ W1,
                                              unsigned short* __restrict__ Abf,
                                              unsigned short* __restrict__ Xbf,
                                              unsigned short* __restrict__ W1bf) {
    const int NT = 1343488;   // 1048576 (A) + 262144 (X) + 32768 (W1) float4 units
    for (int v = blockIdx.x * 256 + threadIdx.x; v < NT; v += gridDim.x * 256) {
        const float* src; unsigned short* dst; int off;
        if (v < 1048576)      { src = A;  dst = Abf;  off = v; }
        else if (v < 1310720) { src = X;  dst = Xbf;  off = v - 1048576; }
        else                  { src = W1; dst = W1bf; off = v - 1310720; }
        float4 f = ((const float4*)src)[off];
        short4 h;
        h.x = (short)f2bf(f.x); h.y = (short)f2bf(f.y);
        h.z = (short)f2bf(f.z); h.w = (short)f2bf(f.w);
        ((short4*)dst)[off] = h;
    }
}

// ---------------- T1: XWt[h][n] = bf16( W1bf @ Xbf^T )  direct-reg MFMA ----------
// 2048 waves: 16 h-tiles x 128 n-tiles, one 16x16 tile per wave, K=512, no LDS.
__global__ __launch_bounds__(256) void t1_mfma(const unsigned short* __restrict__ W1bf,
                                               const unsigned short* __restrict__ Xbf,
                                               unsigned short* __restrict__ XWt) {
    const int wt   = blockIdx.x * 4 + (threadIdx.x >> 6);
    const int lane = threadIdx.x & 63;
    const int h0 = (wt >> 7) * 16;
    const int n0 = (wt & 127) * 16;
    const int lm = lane & 15, lk = (lane >> 4) * 8;
    const unsigned short* ap = W1bf + (size_t)(h0 + lm) * DD + lk;
    const unsigned short* bp = Xbf  + (size_t)(n0 + lm) * DD + lk;
    f32x4 acc = {};
    #pragma unroll 4
    for (int k = 0; k < DD; k += 32) {
        short8 a = *(const short8*)(ap + k);
        short8 b = *(const short8*)(bp + k);
        acc = __builtin_amdgcn_mfma_f32_16x16x32_bf16(a, b, acc, 0, 0, 0);
    }
    const int col = n0 + lm;
    #pragma unroll
    for (int r = 0; r < 4; ++r) {
        int row = h0 + (lane >> 4) * 4 + r;
        XWt[(size_t)row * NNODE + col] = f2bf(acc[r]);
    }
}

// ---------------- T2: Hbf = bf16(leaky(Abf @ XW + b1))  direct-reg MFMA ----------
// 1024 waves: 128 m-tiles x 8 n-pairs, 16x32 tile per wave, K=2048, no LDS.
__global__ __launch_bounds__(256) void t2_mfma(const unsigned short* __restrict__ Abf,
                                               const unsigned short* __restrict__ XWt,
                                               const float* __restrict__ bias1,
                                               unsigned short* __restrict__ Hbf) {
    const int wt   = blockIdx.x * 4 + (threadIdx.x >> 6);
    const int lane = threadIdx.x & 63;
    const int m0 = (wt >> 3) * 16;
    const int n0 = (wt & 7) * 32;
    const int lm = lane & 15, lk = (lane >> 4) * 8;
    const unsigned short* ap  = Abf + (size_t)(m0 + lm) * NNODE + lk;
    const unsigned short* bp0 = XWt + (size_t)(n0 + lm) * NNODE + lk;
    const unsigned short* bp1 = XWt + (size_t)(n0 + 16 + lm) * NNODE + lk;
    f32x4 acc0 = {}, acc1 = {};
    #pragma unroll 4
    for (int k = 0; k < NNODE; k += 32) {
        short8 a  = *(const short8*)(ap + k);
        short8 b0 = *(const short8*)(bp0 + k);
        short8 b1 = *(const short8*)(bp1 + k);
        acc0 = __builtin_amdgcn_mfma_f32_16x16x32_bf16(a, b0, acc0, 0, 0, 0);
        acc1 = __builtin_amdgcn_mfma_f32_16x16x32_bf16(a, b1, acc1, 0, 0, 0);
    }
    const int col0 = n0 + lm, col1 = n0 + 16 + lm;
    const float bv0 = bias1[col0], bv1 = bias1[col1];
    #pragma unroll
    for (int r = 0; r < 4; ++r) {
        int row = m0 + (lane >> 4) * 4 + r;
        float v0 = acc0[r] + bv0;
        float v1 = acc1[r] + bv1;
        v0 = fmaxf(v0, 0.01f * v0);
        v1 = fmaxf(v1, 0.01f * v1);
        Hbf[(size_t)row * HHID + col0] = f2bf(v0);
        Hbf[(size_t)row * HHID + col1] = f2bf(v1);
    }
}

// ---------------- T3: Gt[j][n] = bf16( sum_d Hbf[n][d] * Wcat[j][d] ) ------------
__global__ __launch_bounds__(256) void t3_g(const unsigned short* __restrict__ Hbf,
                                            const float* __restrict__ Wmu,
                                            const float* __restrict__ Wlv,
                                            unsigned short* __restrict__ Gt) {
    __shared__ float Hs[8][260];
    __shared__ float Ws[32][260];
    const int tid = threadIdx.x;
    const int n0 = blockIdx.x * 8;
    #pragma unroll
    for (int s = 0; s < 8; ++s) {
        int idx = tid + s * 256;            // float4 units, 0..2047
        int row = idx >> 6, c = (idx & 63) * 4;
        const float* src = (row < 16) ? (Wmu + (size_t)row * HHID)
                                      : (Wlv + (size_t)(row - 16) * HHID);
        *(float4*)&Ws[row][c] = *(const float4*)(src + c);
    }
    {
        int r = tid >> 5, seg = tid & 31;
        int d = seg * 8;
        ushort4 u0 = *(const ushort4*)(Hbf + (size_t)(n0 + r) * HHID + d);
        ushort4 u1 = *(const ushort4*)(Hbf + (size_t)(n0 + r) * HHID + d + 4);
        Hs[r][d + 0] = bf2f(u0.x); Hs[r][d + 1] = bf2f(u0.y);
        Hs[r][d + 2] = bf2f(u0.z); Hs[r][d + 3] = bf2f(u0.w);
        Hs[r][d + 4] = bf2f(u1.x); Hs[r][d + 5] = bf2f(u1.y);
        Hs[r][d + 6] = bf2f(u1.z); Hs[r][d + 7] = bf2f(u1.w);
    }
    __syncthreads();
    const int r = tid >> 5, j = tid & 31;
    float acc = 0.f;
    #pragma unroll 8
    for (int d4 = 0; d4 < 64; ++d4) {
        float4 a = *(const float4*)&Hs[r][d4 * 4];
        float4 b = *(const float4*)&Ws[j][d4 * 4];
        acc += a.x * b.x + a.y * b.y + a.z * b.z + a.w * b.w;
    }
    Gt[(size_t)j * NNODE + n0 + r] = f2bf(acc);
}

// ---------------- T4: Mp[s] = partial Abf @ G  direct-reg MFMA, splitK=8 ---------
// 2048 waves: 128 m-tiles x 2 n-tiles x 8 ks, 16x16 per wave, K=256 each.
__global__ __launch_bounds__(256) void t4_mfma(const unsigned short* __restrict__ Abf,
                                               const unsigned short* __restrict__ Gt,
                                               float* __restrict__ Mp) {
    const int wt   = blockIdx.x * 4 + (threadIdx.x >> 6);
    const int lane = threadIdx.x & 63;
    const int m0 = (wt >> 4) * 16;
    const int nt = wt & 1;
    const int ks = (wt >> 1) & 7;
    const int n0 = nt * 16;
    const int kbase = ks * 256;
    const int lm = lane & 15, lk = (lane >> 4) * 8;
    const unsigned short* ap = Abf + (size_t)(m0 + lm) * NNODE + kbase + lk;
    const unsigned short* bp = Gt  + (size_t)(n0 + lm) * NNODE + kbase + lk;
    f32x4 acc = {};
    #pragma unroll
    for (int k = 0; k < 256; k += 32) {
        short8 a = *(const short8*)(ap + k);
        short8 b = *(const short8*)(bp + k);
        acc = __builtin_amdgcn_mfma_f32_16x16x32_bf16(a, b, acc, 0, 0, 0);
    }
    float* outp = Mp + (size_t)ks * 65536;
    const int col = n0 + lm;
    #pragma unroll
    for (int r = 0; r < 4; ++r) {
        int row = m0 + (lane >> 4) * 4 + r;
        outp[(size_t)row * H2 + col] = acc[r];
    }
}

// ---------------- T5: reduce Mp; mu/logvar out; Z; P' and Q ----------------------
__global__ __launch_bounds__(256) void t5_z(const float* __restrict__ Mp,
                                            const float* __restrict__ bmu,
                                            const float* __restrict__ blv,
                                            const float* __restrict__ eps,
                                            const float* __restrict__ Wd1,
                                            const float* __restrict__ bd1,
                                            float* __restrict__ out_mu,
                                            float* __restrict__ out_lv,
                                            float* __restrict__ Pp,
                                            float* __restrict__ Qq) {
    __shared__ float Zs[16][16];
    const int tid = threadIdx.x;
    const int n0 = blockIdx.x * 16;
    {
        int nl = tid >> 4, l = tid & 15;
        int n = n0 + nl;
        float m = bmu[l], lv = blv[l];
        #pragma unroll
        for (int s = 0; s < 8; ++s) {
            m  += Mp[(size_t)s * 65536 + (size_t)n * H2 + l];
            lv += Mp[(size_t)s * 65536 + (size_t)n * H2 + 16 + l];
        }
        out_mu[(size_t)n * LLAT + l] = m;
        out_lv[(size_t)n * LLAT + l] = lv;
        Zs[nl][l] = m + eps[(size_t)n * LLAT + l] * __expf(0.5f * lv);
    }
    __syncthreads();
    #pragma unroll
    for (int p = 0; p < 2; ++p) {
        int idx = tid + p * 256;            // 0..511
        int nl = idx >> 5, o = idx & 31;
        int n = n0 + nl;
        float ap = bd1[o], aq = 0.f;
        #pragma unroll
        for (int l = 0; l < 16; ++l) {
            float z = Zs[nl][l];
            ap = fmaf(z, Wd1[o * H2 + l],      ap);
            aq = fmaf(z, Wd1[o * H2 + 16 + l], aq);
        }
        Pp[(size_t)n * H2 + o] = ap;
        Qq[(size_t)n * H2 + o] = aq;
    }
}

// ---------------- T6: A_pred[i][j] = sigmoid(sum_o w2[o]*leaky(P'[i,o]+Q[j,o])+bd2)
__global__ __launch_bounds__(256) void t6_dec(const float* __restrict__ Pp,
                                              const float* __restrict__ Qq,
                                              const float* __restrict__ Wd2,
                                              const float* __restrict__ bd2,
                                              float* __restrict__ Apred) {
    __shared__ float Qt[32][68];   // transposed Q tile, padded
    __shared__ float Ws2[32];
    const int tid = threadIdx.x;
    const int j0 = blockIdx.x * 64, i0 = blockIdx.y * 16;
    #pragma unroll
    for (int s = 0; s < 8; ++s) {
        int idx = tid + s * 256;            // 0..2047
        int j = idx >> 5, o = idx & 31;
        Qt[o][j] = Qq[(size_t)(j0 + j) * H2 + o];
    }
    if (tid < 32) Ws2[tid] = Wd2[tid];
    const int i = i0 + (tid >> 4);
    const int jq = tid & 15;
    float p[32];
    const float4* P4 = (const float4*)(Pp + (size_t)i * H2);
    #pragma unroll
    for (int c = 0; c < 8; ++c) {
        float4 v = P4[c];
        p[c * 4] = v.x; p[c * 4 + 1] = v.y; p[c * 4 + 2] = v.z; p[c * 4 + 3] = v.w;
    }
    __syncthreads();
    f32x4 acc = {0.f, 0.f, 0.f, 0.f};
    #pragma unroll
    for (int o = 0; o < 32; ++o) {
        float4 q = *(const float4*)&Qt[o][jq * 4];
        float w = Ws2[o], po = p[o];
        float s0 = po + q.x, s1 = po + q.y, s2 = po + q.z, s3 = po + q.w;
        // leaky_relu(s) = max(s, 0.01*s)
        acc[0] = fmaf(w, fmaxf(s0, 0.01f * s0), acc[0]);
        acc[1] = fmaf(w, fmaxf(s1, 0.01f * s1), acc[1]);
        acc[2] = fmaf(w, fmaxf(s2, 0.01f * s2), acc[2]);
        acc[3] = fmaf(w, fmaxf(s3, 0.01f * s3), acc[3]);
    }
    float b = bd2[0];
    float4 r;
    r.x = 1.f / (1.f + __expf(-(acc[0] + b)));
    r.y = 1.f / (1.f + __expf(-(acc[1] + b)));
    r.z = 1.f / (1.f + __expf(-(acc[2] + b)));
    r.w = 1.f / (1.f + __expf(-(acc[3] + b)));
    *(float4*)(Apred + (size_t)i * NNODE + j0 + jq * 4) = r;
}

extern "C" void kernel_launch(void* const* d_in, const int* in_sizes, int n_in,
                              void* d_out, int out_size, void* d_ws, size_t ws_size,
                              hipStream_t stream) {
    const float* A   = (const float*)d_in[0];
    const float* X   = (const float*)d_in[1];
    const float* eps = (const float*)d_in[2];
    const float* W1  = (const float*)d_in[3];
    const float* b1  = (const float*)d_in[4];
    const float* Wmu = (const float*)d_in[5];
    const float* bmu = (const float*)d_in[6];
    const float* Wlv = (const float*)d_in[7];
    const float* blv = (const float*)d_in[8];
    const float* Wd1 = (const float*)d_in[9];
    const float* bd1 = (const float*)d_in[10];
    const float* Wd2 = (const float*)d_in[11];
    const float* bd2 = (const float*)d_in[12];
    float* out = (float*)d_out;
    char* ws = (char*)d_ws;

    // workspace carve (~15.6 MB), every buffer fully overwritten each call
    unsigned short* Abf  = (unsigned short*)(ws);               //  8,388,608
    unsigned short* Xbf  = (unsigned short*)(ws + 8388608);     //  2,097,152
    unsigned short* W1bf = (unsigned short*)(ws + 10485760);    //    262,144
    unsigned short* XWt  = (unsigned short*)(ws + 10747904);    //  1,048,576
    unsigned short* Hbf  = (unsigned short*)(ws + 11796480);    //  1,048,576
    unsigned short* Gt   = (unsigned short*)(ws + 12845056);    //    131,072
    float*          Mp   = (float*)(ws + 12976128);             //  2,097,152 (8 x 256KB)
    float*          Pp   = (float*)(ws + 15073280);             //    262,144
    float*          Qq   = (float*)(ws + 15335424);             //    262,144

    float* out_mu = out + (size_t)NNODE * NNODE;
    float* out_lv = out_mu + NNODE * LLAT;

    t0_cvt <<<1024,          256, 0, stream>>>(A, X, W1, Abf, Xbf, W1bf);
    t1_mfma<<<512,           256, 0, stream>>>(W1bf, Xbf, XWt);
    t2_mfma<<<256,           256, 0, stream>>>(Abf, XWt, b1, Hbf);
    t3_g   <<<256,           256, 0, stream>>>(Hbf, Wmu, Wlv, Gt);
    t4_mfma<<<512,           256, 0, stream>>>(Abf, Gt, Mp);
    t5_z   <<<128,           256, 0, stream>>>(Mp, bmu, blv, eps, Wd1, bd1,
                                               out_mu, out_lv, Pp, Qq);
    t6_dec <<<dim3(32, 128), 256, 0, stream>>>(Pp, Qq, Wd2, bd2, out);
}